// Round 5
// baseline (353.412 us; speedup 1.0000x reference)
//
#include <hip/hip_runtime.h>
#include <math.h>

#define VOCAB 50000
#define DW 300
#define DH 50
#define G4 200
#define BATCH 1024
#define TMAX 200
#define OUTC 4

typedef float f4 __attribute__((ext_vector_type(4)));

// ---------------------------------------------------------------------------
// Kernel 0: transpose + gate-permute w_ih [200][300] -> w_T [300][200] with
// columns u2 = (u%50)*4 + u/50 (unit-major, gate-minor).
__global__ __launch_bounds__(256) void transpose_wih(
    const float* __restrict__ w_ih, float* __restrict__ w_T)
{
    int i = blockIdx.x * 256 + threadIdx.x;
    if (i < G4 * DW) {
        int u = i / DW, k = i % DW;
        int u2 = (u % DH) * 4 + (u / DH);
        w_T[k * G4 + u2] = w_ih[i];
    }
}

// ---------------------------------------------------------------------------
// Kernel A: emb_proj[v][u2] = sum_k emb[v][k]*w_ih[u][k] + b_ih[u] + b_hh[u]
// (unchanged — isolation; it gets its own pass once it tops the profile)
__global__ __launch_bounds__(256, 2) void proj_kernel(
    const float* __restrict__ emb, const float* __restrict__ w_T,
    const float* __restrict__ b_ih, const float* __restrict__ b_hh,
    float* __restrict__ emb_proj)
{
    __shared__ __align__(16) float e_s[100 * 108];  // rows padded to 108 dwords
    const int tid = threadIdx.x;
    const int v0 = blockIdx.x * 100;
    const int m_idx = tid / 25;   // 0..9 (valid for tid<250)
    const int n_idx = tid % 25;   // 0..24

    float acc[10][8];
#pragma unroll
    for (int m = 0; m < 10; m++)
#pragma unroll
        for (int c = 0; c < 8; c++) acc[m][c] = 0.f;

    const float* wcol = w_T + n_idx * 8;

    for (int kc = 0; kc < DW; kc += 100) {
        __syncthreads();   // protect previous chunk reads
        for (int i = tid; i < 2500; i += 256) {
            int r = i / 25, c = i % 25;
            float4 v = *(const float4*)&emb[(size_t)(v0 + r) * DW + kc + c * 4];
            *(float4*)&e_s[r * 108 + c * 4] = v;
        }
        __syncthreads();

        if (tid < 250) {
            float4 wa[4], wb[4];
#pragma unroll
            for (int j = 0; j < 4; j++) {
                const float* p = wcol + (size_t)(kc + j) * G4;
                wa[j] = *(const float4*)p;
                wb[j] = *(const float4*)(p + 4);
            }
            for (int kk = 0; kk < 25; kk++) {
                float4 na[4], nb[4];
                int kn = kc + ((kk < 24) ? (kk + 1) : kk) * 4;
#pragma unroll
                for (int j = 0; j < 4; j++) {
                    const float* p = wcol + (size_t)(kn + j) * G4;
                    na[j] = *(const float4*)p;
                    nb[j] = *(const float4*)(p + 4);
                }
                float4 e4[10];
#pragma unroll
                for (int m = 0; m < 10; m++)
                    e4[m] = *(const float4*)&e_s[(m_idx * 10 + m) * 108 + kk * 4];
#pragma unroll
                for (int j = 0; j < 4; j++) {
#pragma unroll
                    for (int m = 0; m < 10; m++) {
                        float ev = (j == 0) ? e4[m].x : (j == 1) ? e4[m].y
                                 : (j == 2) ? e4[m].z : e4[m].w;
                        acc[m][0] = fmaf(ev, wa[j].x, acc[m][0]);
                        acc[m][1] = fmaf(ev, wa[j].y, acc[m][1]);
                        acc[m][2] = fmaf(ev, wa[j].z, acc[m][2]);
                        acc[m][3] = fmaf(ev, wa[j].w, acc[m][3]);
                        acc[m][4] = fmaf(ev, wb[j].x, acc[m][4]);
                        acc[m][5] = fmaf(ev, wb[j].y, acc[m][5]);
                        acc[m][6] = fmaf(ev, wb[j].z, acc[m][6]);
                        acc[m][7] = fmaf(ev, wb[j].w, acc[m][7]);
                    }
                }
#pragma unroll
                for (int j = 0; j < 4; j++) { wa[j] = na[j]; wb[j] = nb[j]; }
            }
        }
    }

    if (tid < 250) {
        float bias[8];
#pragma unroll
        for (int c = 0; c < 8; c++) {
            int u2 = n_idx * 8 + c;
            int u  = (u2 & 3) * DH + (u2 >> 2);   // inverse gate permutation
            bias[c] = b_ih[u] + b_hh[u];
        }
#pragma unroll
        for (int m = 0; m < 10; m++) {
            float* dst = &emb_proj[(size_t)(v0 + m_idx * 10 + m) * G4 + n_idx * 8];
            *(float4*)dst = make_float4(acc[m][0] + bias[0], acc[m][1] + bias[1],
                                        acc[m][2] + bias[2], acc[m][3] + bias[3]);
            *(float4*)(dst + 4) = make_float4(acc[m][4] + bias[4], acc[m][5] + bias[5],
                                              acc[m][6] + bias[6], acc[m][7] + bias[7]);
        }
    }
}

// ---------------------------------------------------------------------------
// Kernel P: pack per-thread w_hh rows for the lstm kernel.
// Thread t of the lstm block owns gates {2*(t&1), 2*(t&1)+1} of unit t>>1.
// wp[t] = [rowA(50) pad2 | rowB(50) pad2] -> 104 floats, 416B stride (16B ok).
__global__ __launch_bounds__(128) void prep_whh(
    const float* __restrict__ w_hh, float* __restrict__ wp)
{
    int t = threadIdx.x;
    int odd = t & 1, u = t >> 1;
    int uu = (u < DH) ? u : 0;
#pragma unroll
    for (int s = 0; s < 2; s++) {
        int gate = 2 * odd + s;
        const float* src = w_hh + (size_t)(gate * DH + uu) * DH;
        float* dst = wp + t * 104 + s * 52;
        for (int k = 0; k < DH; k++) dst[k] = src[k];
        dst[50] = 0.f; dst[51] = 0.f;
    }
}

// ---------------------------------------------------------------------------
// Kernel B: round-1 structure (verified passing): 2 waves/block, thread owns
// 2 gate rows of unit tid/2 (even: i,f; odd: c,o), DPP quad exchange, one
// barrier/step. NEW: W loaded via asm-volatile global_load_dwordx4 into 26
// NAMED ext-vector float4s. An asm result can be neither rematerialized nor
// sunk into the loop — the escape route the scheduler used in rounds 0-4
// (VGPR 140/68/44/140, W re-streamed from L2 at ~36 TB/s = the measured L2
// roofline) is closed. Budget: ~150 live regs < 256/wave at 2 waves/EU.
__device__ __forceinline__ float dpp_xor1(float x) {
    // quad_perm [1,0,3,2] : lane 0<->1, 2<->3 within each quad
    return __int_as_float(__builtin_amdgcn_update_dpp(
        0, __float_as_int(x), 0xB1, 0xF, 0xF, true));
}

__global__ __launch_bounds__(128, 2) void lstm_kernel(
    const int* __restrict__ x, const int* __restrict__ lengs,
    const float* __restrict__ emb_proj, const float* __restrict__ wp,
    const float* __restrict__ w_out, const float* __restrict__ b_out,
    float* __restrict__ out)
{
    __shared__ __align__(16) float hbuf[2][52];
    __shared__ int x_s[TMAX];
    __shared__ float red[OUTC];

    const int tid = threadIdx.x;
    const int b   = blockIdx.x;
    const int u   = tid >> 1;              // unit 0..63 (>=50 are spares)
    const int odd = tid & 1;               // 0: gates i,f ; 1: gates c,o
    const int len = lengs[b];

    for (int i = tid; i < TMAX; i += 128) x_s[i] = x[b * TMAX + i];
    if (tid < 52) hbuf[0][tid] = 0.f;

    // ---- W load: 26 asm-volatile dwordx4 into named registers ----
    const float* wbase = wp + (size_t)tid * 104;
    f4 WA0, WA1, WA2, WA3, WA4, WA5, WA6, WA7, WA8, WA9, WA10, WA11, WA12;
    f4 WB0, WB1, WB2, WB3, WB4, WB5, WB6, WB7, WB8, WB9, WB10, WB11, WB12;
#define LDW(dst, OFF)                                                         \
    asm volatile("global_load_dwordx4 %0, %1, off offset:" #OFF              \
                 : "=v"(dst) : "v"(wbase));
    LDW(WA0,   0) LDW(WA1,  16) LDW(WA2,  32) LDW(WA3,  48) LDW(WA4,  64)
    LDW(WA5,  80) LDW(WA6,  96) LDW(WA7, 112) LDW(WA8, 128) LDW(WA9, 144)
    LDW(WA10,160) LDW(WA11,176) LDW(WA12,192)
    LDW(WB0, 208) LDW(WB1, 224) LDW(WB2, 240) LDW(WB3, 256) LDW(WB4, 272)
    LDW(WB5, 288) LDW(WB6, 304) LDW(WB7, 320) LDW(WB8, 336) LDW(WB9, 352)
    LDW(WB10,368) LDW(WB11,384) LDW(WB12,400)
#undef LDW
    asm volatile("s_waitcnt vmcnt(0)" ::: "memory");
    __syncthreads();

    // gather columns: unit-major gate-minor layout => cols {4u+2*odd, +1}
    const int col = (u < DH) ? (tid * 2) : 0;
    const float* ep = emb_proj;
    float2 p0 = *(const float2*)(ep + (size_t)x_s[0] * G4 + col);
    float2 p1 = *(const float2*)(ep + (size_t)x_s[1] * G4 + col);
    float2 p2 = *(const float2*)(ep + (size_t)x_s[2] * G4 + col);
    float c_reg = 0.f;

    for (int t = 0; t < len; t++) {
        float2 cur = p0; p0 = p1; p1 = p2;
        int nt = t + 3; nt = (nt < TMAX) ? nt : TMAX - 1;
        p2 = *(const float2*)(ep + (size_t)x_s[nt] * G4 + col);

        const float* hb = hbuf[t & 1];
        float4 h0  = *(const float4*)(hb + 0);
        float4 h1  = *(const float4*)(hb + 4);
        float4 h2  = *(const float4*)(hb + 8);
        float4 h3  = *(const float4*)(hb + 12);
        float4 h4  = *(const float4*)(hb + 16);
        float4 h5  = *(const float4*)(hb + 20);
        float4 h6  = *(const float4*)(hb + 24);
        float4 h7  = *(const float4*)(hb + 28);
        float4 h8  = *(const float4*)(hb + 32);
        float4 h9  = *(const float4*)(hb + 36);
        float4 h10 = *(const float4*)(hb + 40);
        float4 h11 = *(const float4*)(hb + 44);
        float2 h12 = *(const float2*)(hb + 48);

#define DOT4(A, H, W)                                                         \
        A = fmaf((H).x, (W).x, fmaf((H).y, (W).y,                             \
            fmaf((H).z, (W).z, fmaf((H).w, (W).w, A))));
        float accA0 = cur.x, accA1 = 0.f, accB0 = cur.y, accB1 = 0.f;
        DOT4(accA0, h0,  WA0)  DOT4(accB0, h0,  WB0)
        DOT4(accA1, h1,  WA1)  DOT4(accB1, h1,  WB1)
        DOT4(accA0, h2,  WA2)  DOT4(accB0, h2,  WB2)
        DOT4(accA1, h3,  WA3)  DOT4(accB1, h3,  WB3)
        DOT4(accA0, h4,  WA4)  DOT4(accB0, h4,  WB4)
        DOT4(accA1, h5,  WA5)  DOT4(accB1, h5,  WB5)
        DOT4(accA0, h6,  WA6)  DOT4(accB0, h6,  WB6)
        DOT4(accA1, h7,  WA7)  DOT4(accB1, h7,  WB7)
        DOT4(accA0, h8,  WA8)  DOT4(accB0, h8,  WB8)
        DOT4(accA1, h9,  WA9)  DOT4(accB1, h9,  WB9)
        DOT4(accA0, h10, WA10) DOT4(accB0, h10, WB10)
        DOT4(accA1, h11, WA11) DOT4(accB1, h11, WB11)
        accA0 = fmaf(h12.x, WA12.x, fmaf(h12.y, WA12.y, accA0));
        accB1 = fmaf(h12.x, WB12.x, fmaf(h12.y, WB12.y, accB1));
#undef DOT4
        float gA = accA0 + accA1;
        float gB = accB0 + accB1;

        // even: vA=sig(i), vB=sig(f) ; odd: vA=tanh(c), vB=sig(o)
        float yA = odd ? 2.f * gA : gA;
        float sA = 1.f / (1.f + __expf(-yA));
        float vA = odd ? fmaf(2.f, sA, -1.f) : sA;
        float vB = 1.f / (1.f + __expf(-gB));

        float oA = dpp_xor1(vA);
        float oB = dpp_xor1(vB);
        float si = odd ? oA : vA;
        float sf = odd ? oB : vB;
        float tg = odd ? vA : oA;
        float so = odd ? vB : oB;

        float cn = fmaf(sf, c_reg, si * tg);
        c_reg = cn;                       // identical on both pair threads
        float th = fmaf(2.f, 1.f / (1.f + __expf(-2.f * cn)), -1.f);
        float hn = so * th;
        if (!odd && u < DH) hbuf[(t + 1) & 1][u] = hn;
        __syncthreads();
    }

    // logits + softmax (threads 0-3, all in wave 0: LDS ops program-ordered)
    const float* hf = hbuf[len & 1];
    if (tid < OUTC) {
        float lg = b_out[tid];
        const float* wo = w_out + tid * DH;
#pragma unroll
        for (int k = 0; k < DH; k++) lg = fmaf(hf[k], wo[k], lg);
        red[tid] = lg;
    }
    if (tid < OUTC) {
        float m = fmaxf(fmaxf(red[0], red[1]), fmaxf(red[2], red[3]));
        float s = 0.f;
#pragma unroll
        for (int j = 0; j < OUTC; j++) s += __expf(red[j] - m);
        out[b * OUTC + tid] = __expf(red[tid] - m) / s;
    }
}

// ---------------------------------------------------------------------------
extern "C" void kernel_launch(void* const* d_in, const int* in_sizes, int n_in,
                              void* d_out, int out_size, void* d_ws, size_t ws_size,
                              hipStream_t stream) {
    const int*   x     = (const int*)d_in[0];
    const int*   lengs = (const int*)d_in[1];
    const float* emb   = (const float*)d_in[2];
    const float* w_ih  = (const float*)d_in[3];
    const float* w_hh  = (const float*)d_in[4];
    const float* b_ih  = (const float*)d_in[5];
    const float* b_hh  = (const float*)d_in[6];
    const float* w_out = (const float*)d_in[7];
    const float* b_out = (const float*)d_in[8];
    float* out = (float*)d_out;

    float* emb_proj = (float*)d_ws;                       // 40 MB
    float* w_T      = emb_proj + (size_t)VOCAB * G4;      // +240 KB
    float* wp       = w_T;   // reuse: w_T dead after proj_kernel completes
                             // (stream-ordered; prep_whh launches after proj)

    hipLaunchKernelGGL(transpose_wih, dim3((G4 * DW + 255) / 256), dim3(256),
                       0, stream, w_ih, w_T);
    hipLaunchKernelGGL(proj_kernel, dim3(VOCAB / 100), dim3(256), 0, stream,
                       emb, w_T, b_ih, b_hh, emb_proj);
    hipLaunchKernelGGL(prep_whh, dim3(1), dim3(128), 0, stream, w_hh, wp);
    hipLaunchKernelGGL(lstm_kernel, dim3(BATCH), dim3(128), 0, stream,
                       x, lengs, emb_proj, wp, w_out, b_out, out);
}